// Round 5
// baseline (89.672 us; speedup 1.0000x reference)
//
#include <hip/hip_runtime.h>
#include <hip/hip_bf16.h>

#define OUTN 11008
#define KDIM 4096
#define BDIM 32
#define NT   344          // OUTN / 32
#define WCOUNT 45088768   // OUTN * KDIM
#define NKS  4            // K-splits (one per wave-quad block)

typedef __bf16 bf16x8 __attribute__((ext_vector_type(8)));
typedef float f32x16 __attribute__((ext_vector_type(16)));

__device__ __forceinline__ ushort f2bf(float f) {
    unsigned u = __builtin_bit_cast(unsigned, f);
    u = (u + 0x7FFFu + ((u >> 16) & 1u)) >> 16;
    return (ushort)u;
}

// ternary as f32 bits: sign(w)*1.0f if |w|>d else 0
__device__ __forceinline__ unsigned tern1(float w, float d) {
    unsigned b = __builtin_bit_cast(unsigned, w);
    unsigned s = (b & 0x80000000u) | 0x3F800000u;
    return (__builtin_fabsf(w) > d) ? s : 0u;
}
// pack two ternary values as 2 bf16 (a -> low 16, b -> high 16)
__device__ __forceinline__ unsigned ternpack(float a, float b, float d) {
    return __builtin_amdgcn_perm(tern1(b, d), tern1(a, d), 0x07060302u);
}

__device__ __forceinline__ float delta_from(const double* dsum) {
    const double delta_d = 0.7 * (*dsum) * (1.0 / (double)WCOUNT);
    float dc = (float)delta_d;
    if ((double)dc > delta_d)          // largest f32 <= delta_f64
        dc = __builtin_bit_cast(float, __builtin_bit_cast(unsigned, dc) - 1u);
    return dc;
}

// ---------------- pass 1: sum(|W|) in f64; exact 43 iters/thread ----------------
__global__ __launch_bounds__(256) void abssum_k(const float4* __restrict__ w4,
                                                double* __restrict__ dsum) {
    const int tid = blockIdx.x * 256 + threadIdx.x;    // grid fixed at 1024 blocks
    double s = 0.0;
#pragma unroll 8
    for (int j = 0; j < 43; ++j) {                     // 262144 * 43 == WCOUNT/4
        float4 v = w4[tid + j * 262144];
        s += (double)(fabsf(v.x) + fabsf(v.y)) + (double)(fabsf(v.z) + fabsf(v.w));
    }
    for (int off = 32; off; off >>= 1) s += __shfl_down(s, off);
    __shared__ double red[4];
    const int lane = threadIdx.x & 63, wv = threadIdx.x >> 6;
    if (lane == 0) red[wv] = s;
    __syncthreads();
    if (threadIdx.x == 0) atomicAdd(dsum, red[0] + red[1] + red[2] + red[3]);
}

// ---------------- pass 0: x f32 -> bf16 fragment-ordered [K/8][32][8]; zeroes dsum ----------------
__global__ __launch_bounds__(256) void xconv_k(const float* __restrict__ x,
                                               ushort* __restrict__ xb,
                                               double* __restrict__ dsum) {
    const int i4 = blockIdx.x * 256 + threadIdx.x;     // exactly 32768 float4s
    if (i4 == 0) *dsum = 0.0;                          // runs before abssum (stream order)
    const int elem = i4 * 4;
    const int b = elem >> 12;
    const int k = elem & (KDIM - 1);
    const float4 v = ((const float4*)x)[i4];
    ushort4 o;
    o.x = f2bf(v.x); o.y = f2bf(v.y); o.z = f2bf(v.z); o.w = f2bf(v.w);
    const int ofs = ((k >> 3) * 32 + b) * 8 + (k & 7);
    *(ushort4*)(xb + ofs) = o;
}

// ---------------- pass 2: fused ternarize + MFMA GEMM, 4 waves/block ----------------
// block = 256 thr = 4 waves; each wave: 32x32 tile over a 256-K quarter of the
// block's 1024-K chunk; W loaded directly in B-fragment layout, ternarized in regs;
// 4-way LDS reduce -> one partial per block.
__global__ __launch_bounds__(256, 5) void gemm4_k(const float* __restrict__ W,
                                                  const ushort* __restrict__ xb,
                                                  const double* __restrict__ dsum,
                                                  float* __restrict__ part) {
    __shared__ float red[3][32][32];
    const int wv = threadIdx.x >> 6;
    const int l = threadIdx.x & 63;
    const int tile = blockIdx.x % NT;
    const int ksid = blockIdx.x / NT;                  // 0..NKS-1
    const int o0 = tile * 32;
    const int kw0 = ksid * (KDIM / NKS) + wv * 256;    // this wave's K range (256 wide)

    const float delta = delta_from(dsum);
    const int row = l & 31, half = l >> 5;
    const float4* wp = (const float4*)(W + (size_t)(o0 + row) * KDIM + kw0 + half * 8);
    const uint4* xa = (const uint4*)xb + ((size_t)(kw0 >> 3) + half) * 32 + row;

    f32x16 acc;
#pragma unroll
    for (int i = 0; i < 16; ++i) acc[i] = 0.0f;

#pragma unroll
    for (int s = 0; s < 16; ++s) {                     // 16 MFMA steps of K=16
        float4 w0 = wp[s * 4], w1 = wp[s * 4 + 1];
        uint4 a4 = xa[(size_t)s * 64];
        uint4 bb;
        bb.x = ternpack(w0.x, w0.y, delta);
        bb.y = ternpack(w0.z, w0.w, delta);
        bb.z = ternpack(w1.x, w1.y, delta);
        bb.w = ternpack(w1.z, w1.w, delta);
        acc = __builtin_amdgcn_mfma_f32_32x32x16_bf16(
                  __builtin_bit_cast(bf16x8, a4), __builtin_bit_cast(bf16x8, bb),
                  acc, 0, 0, 0);
    }

    if (wv > 0) {
#pragma unroll
        for (int rg = 0; rg < 16; ++rg) {
            const int m = (rg & 3) + 8 * (rg >> 2) + 4 * half;
            red[wv - 1][m][row] = acc[rg];
        }
    }
    __syncthreads();
    if (wv == 0) {
        float* po = part + (size_t)ksid * (BDIM * OUTN);
#pragma unroll
        for (int rg = 0; rg < 16; ++rg) {
            const int m = (rg & 3) + 8 * (rg >> 2) + 4 * half;
            float v = acc[rg] + red[0][m][row] + red[1][m][row] + red[2][m][row];
            po[(size_t)m * OUTN + o0 + row] = v;
        }
    }
}

// ---------------- fallback: single-wave register GEMM (KS=1, direct out) ----------------
template <bool XBF>
__global__ __launch_bounds__(64) void gemm1_k(const float* __restrict__ W,
                                              const float* __restrict__ x,
                                              const ushort* __restrict__ xb,
                                              const double* __restrict__ dsum,
                                              float* __restrict__ dst,
                                              const float* __restrict__ alpha,
                                              const float* __restrict__ bias) {
    const int l = threadIdx.x;
    const int o0 = blockIdx.x * 32;
    const float delta = delta_from(dsum);
    const int row = l & 31, half = l >> 5;
    const float4* wp = (const float4*)(W + (size_t)(o0 + row) * KDIM + half * 8);
    const uint4* xa = (const uint4*)xb + (size_t)half * 32 + row;
    const float4* xp = (const float4*)(x + (size_t)row * KDIM + half * 8);

    f32x16 acc;
#pragma unroll
    for (int i = 0; i < 16; ++i) acc[i] = 0.0f;

#pragma unroll 8
    for (int s = 0; s < 256; ++s) {
        float4 w0 = wp[s * 4], w1 = wp[s * 4 + 1];
        uint4 bb;
        bb.x = ternpack(w0.x, w0.y, delta);
        bb.y = ternpack(w0.z, w0.w, delta);
        bb.z = ternpack(w1.x, w1.y, delta);
        bb.w = ternpack(w1.z, w1.w, delta);
        bf16x8 av;
        if constexpr (XBF) {
            av = __builtin_bit_cast(bf16x8, xa[(size_t)s * 64]);
        } else {
            float4 v0 = xp[s * 4], v1 = xp[s * 4 + 1];
            struct U { ushort s[8]; } uu;
            uu.s[0] = f2bf(v0.x); uu.s[1] = f2bf(v0.y);
            uu.s[2] = f2bf(v0.z); uu.s[3] = f2bf(v0.w);
            uu.s[4] = f2bf(v1.x); uu.s[5] = f2bf(v1.y);
            uu.s[6] = f2bf(v1.z); uu.s[7] = f2bf(v1.w);
            av = __builtin_bit_cast(bf16x8, uu);
        }
        acc = __builtin_amdgcn_mfma_f32_32x32x16_bf16(
                  av, __builtin_bit_cast(bf16x8, bb), acc, 0, 0, 0);
    }
    const float a = *alpha;
#pragma unroll
    for (int rg = 0; rg < 16; ++rg) {
        const int m = (rg & 3) + 8 * (rg >> 2) + 4 * half;
        const int n = o0 + row;
        dst[(size_t)m * OUTN + n] = fmaf(a, acc[rg], bias[n]);
    }
}

// ---------------- pass 3: combine K-split partials + alpha + bias ----------------
__global__ __launch_bounds__(256) void combine_k(const float4* __restrict__ part,
                                                 const float* __restrict__ alpha,
                                                 const float4* __restrict__ bias4,
                                                 float4* __restrict__ out4) {
    const int i = blockIdx.x * 256 + threadIdx.x;   // exactly 88064
    const float a = *alpha;
    float4 s = part[i];
#pragma unroll
    for (int k = 1; k < NKS; ++k) {
        float4 p = part[i + (size_t)k * (BDIM * OUTN / 4)];
        s.x += p.x; s.y += p.y; s.z += p.z; s.w += p.w;
    }
    const float4 b = bias4[i % (OUTN / 4)];
    float4 o;
    o.x = fmaf(a, s.x, b.x); o.y = fmaf(a, s.y, b.y);
    o.z = fmaf(a, s.z, b.z); o.w = fmaf(a, s.w, b.w);
    out4[i] = o;
}

extern "C" void kernel_launch(void* const* d_in, const int* in_sizes, int n_in,
                              void* d_out, int out_size, void* d_ws, size_t ws_size,
                              hipStream_t stream) {
    const float* x     = (const float*)d_in[0];
    const float* W     = (const float*)d_in[1];
    const float* alpha = (const float*)d_in[2];
    const float* bias  = (const float*)d_in[3];
    float* out = (float*)d_out;

    double* dsum = (double*)d_ws;
    const size_t XBF_OFF = 1024;
    const size_t XBF_SZ  = (size_t)BDIM * KDIM * 2;              // 256 KiB
    const size_t PART_OFF = XBF_OFF + XBF_SZ;
    const size_t PART_SZ  = (size_t)NKS * BDIM * OUTN * 4;       // 21.5 MiB

    const bool use_xbf = ws_size >= XBF_OFF + XBF_SZ;
    const bool use_ks  = use_xbf && ws_size >= PART_OFF + PART_SZ;

    ushort* xb = (ushort*)((char*)d_ws + XBF_OFF);
    if (use_xbf) {
        xconv_k<<<128, 256, 0, stream>>>(x, xb, dsum);           // also zeroes dsum
    } else {
        (void)hipMemsetAsync(d_ws, 0, 64, stream);
    }

    abssum_k<<<1024, 256, 0, stream>>>((const float4*)W, dsum);

    if (use_ks) {
        float* part = (float*)((char*)d_ws + PART_OFF);
        gemm4_k<<<NT * NKS, 256, 0, stream>>>(W, xb, dsum, part);
        combine_k<<<344, 256, 0, stream>>>((const float4*)part, alpha,
                                           (const float4*)bias, (float4*)out);
    } else if (use_xbf) {
        gemm1_k<true><<<NT, 64, 0, stream>>>(W, x, xb, dsum, out, alpha, bias);
    } else {
        gemm1_k<false><<<NT, 64, 0, stream>>>(W, x, nullptr, dsum, out, alpha, bias);
    }
}

// Round 6
// 85.366 us; speedup vs baseline: 1.0504x; 1.0504x over previous
//
#include <hip/hip_runtime.h>
#include <hip/hip_bf16.h>

#define OUTN 11008
#define KDIM 4096
#define BDIM 32
#define NT   344          // OUTN / 32
#define WCOUNT 45088768   // OUTN * KDIM
#define NKS  16           // K-splits
#define PF   8            // software-pipeline depth (power of 2)

typedef __bf16 bf16x8 __attribute__((ext_vector_type(8)));
typedef float f32x16 __attribute__((ext_vector_type(16)));

__device__ __forceinline__ ushort f2bf(float f) {
    unsigned u = __builtin_bit_cast(unsigned, f);
    u = (u + 0x7FFFu + ((u >> 16) & 1u)) >> 16;
    return (ushort)u;
}

// ternary as f32 bits: sign(w)*1.0f if |w|>d else 0
__device__ __forceinline__ unsigned tern1(float w, float d) {
    unsigned b = __builtin_bit_cast(unsigned, w);
    unsigned s = (b & 0x80000000u) | 0x3F800000u;
    return (__builtin_fabsf(w) > d) ? s : 0u;
}
// pack two ternary values as 2 bf16 (a -> low 16, b -> high 16)
__device__ __forceinline__ unsigned ternpack(float a, float b, float d) {
    return __builtin_amdgcn_perm(tern1(b, d), tern1(a, d), 0x07060302u);
}

__device__ __forceinline__ float delta_from(const double* dsum) {
    const double delta_d = 0.7 * (*dsum) * (1.0 / (double)WCOUNT);
    float dc = (float)delta_d;
    if ((double)dc > delta_d)          // largest f32 <= delta_f64
        dc = __builtin_bit_cast(float, __builtin_bit_cast(unsigned, dc) - 1u);
    return dc;
}

// ---------------- pass 1: sum(|W|) in f64; exact 43 iters/thread ----------------
__global__ __launch_bounds__(256) void abssum_k(const float4* __restrict__ w4,
                                                double* __restrict__ dsum) {
    const int tid = blockIdx.x * 256 + threadIdx.x;    // grid fixed at 1024 blocks
    double s = 0.0;
#pragma unroll 8
    for (int j = 0; j < 43; ++j) {                     // 262144 * 43 == WCOUNT/4
        float4 v = w4[tid + j * 262144];
        s += (double)(fabsf(v.x) + fabsf(v.y)) + (double)(fabsf(v.z) + fabsf(v.w));
    }
    for (int off = 32; off; off >>= 1) s += __shfl_down(s, off);
    __shared__ double red[4];
    const int lane = threadIdx.x & 63, wv = threadIdx.x >> 6;
    if (lane == 0) red[wv] = s;
    __syncthreads();
    if (threadIdx.x == 0) atomicAdd(dsum, red[0] + red[1] + red[2] + red[3]);
}

// ---------------- pass 0: x f32 -> bf16 fragment-ordered [K/8][32][8]; zeroes dsum ----------------
__global__ __launch_bounds__(256) void xconv_k(const float* __restrict__ x,
                                               ushort* __restrict__ xb,
                                               double* __restrict__ dsum) {
    const int i4 = blockIdx.x * 256 + threadIdx.x;     // exactly 32768 float4s
    if (i4 == 0) *dsum = 0.0;                          // runs before abssum (stream order)
    const int elem = i4 * 4;
    const int b = elem >> 12;
    const int k = elem & (KDIM - 1);
    const float4 v = ((const float4*)x)[i4];
    ushort4 o;
    o.x = f2bf(v.x); o.y = f2bf(v.y); o.z = f2bf(v.z); o.w = f2bf(v.w);
    const int ofs = ((k >> 3) * 32 + b) * 8 + (k & 7);
    *(ushort4*)(xb + ofs) = o;
}

// ---------------- pass 2: fused ternarize + MFMA GEMM, modulo-pipelined ----------------
// one wave per block; 32x32 tile over a 256-wide K-chunk; W loaded directly in
// B-fragment layout, ternarized in regs; PF-deep static-indexed register pipeline.
__global__ __launch_bounds__(64, 3) void gemm_k(const float* __restrict__ W,
                                                const ushort* __restrict__ xb,
                                                const double* __restrict__ dsum,
                                                float* __restrict__ part) {
    constexpr int KCH = KDIM / NKS;        // 256
    constexpr int NSTEP = KCH / 16;        // 16
    const int l = threadIdx.x;
    const int tile = blockIdx.x % NT;
    const int ksid = blockIdx.x / NT;      // 0..NKS-1
    const int o0 = tile * 32;
    const int kw0 = ksid * KCH;

    const float delta = delta_from(dsum);
    const int row = l & 31, half = l >> 5;
    const float4* wp = (const float4*)(W + (size_t)(o0 + row) * KDIM + kw0 + half * 8);
    const uint4* xa = (const uint4*)xb + ((size_t)(kw0 >> 3) + half) * 32 + row;

    f32x16 acc;
#pragma unroll
    for (int i = 0; i < 16; ++i) acc[i] = 0.0f;

    float4 Wa[PF], Wb[PF];
    uint4  XA[PF];
#pragma unroll
    for (int p = 0; p < PF; ++p) {         // prologue: PF steps in flight
        Wa[p] = wp[p * 4];
        Wb[p] = wp[p * 4 + 1];
        XA[p] = xa[(size_t)p * 64];
    }
#pragma unroll
    for (int s = 0; s < NSTEP; ++s) {
        const int b = s & (PF - 1);        // compile-time after full unroll
        uint4 bb;
        bb.x = ternpack(Wa[b].x, Wa[b].y, delta);
        bb.y = ternpack(Wa[b].z, Wa[b].w, delta);
        bb.z = ternpack(Wb[b].x, Wb[b].y, delta);
        bb.w = ternpack(Wb[b].z, Wb[b].w, delta);
        acc = __builtin_amdgcn_mfma_f32_32x32x16_bf16(
                  __builtin_bit_cast(bf16x8, XA[b]), __builtin_bit_cast(bf16x8, bb),
                  acc, 0, 0, 0);
        if (s + PF < NSTEP) {              // refill the slot just consumed
            Wa[b] = wp[(s + PF) * 4];
            Wb[b] = wp[(s + PF) * 4 + 1];
            XA[b] = xa[(size_t)(s + PF) * 64];
        }
    }

    float* po = part + (size_t)ksid * (BDIM * OUTN);
#pragma unroll
    for (int rg = 0; rg < 16; ++rg) {
        const int m = (rg & 3) + 8 * (rg >> 2) + 4 * half;
        po[(size_t)m * OUTN + o0 + row] = acc[rg];
    }
}

// ---------------- fallback: single-wave register GEMM (KS=1, direct out) ----------------
template <bool XBF>
__global__ __launch_bounds__(64) void gemm1_k(const float* __restrict__ W,
                                              const float* __restrict__ x,
                                              const ushort* __restrict__ xb,
                                              const double* __restrict__ dsum,
                                              float* __restrict__ dst,
                                              const float* __restrict__ alpha,
                                              const float* __restrict__ bias) {
    const int l = threadIdx.x;
    const int o0 = blockIdx.x * 32;
    const float delta = delta_from(dsum);
    const int row = l & 31, half = l >> 5;
    const float4* wp = (const float4*)(W + (size_t)(o0 + row) * KDIM + half * 8);
    const uint4* xa = (const uint4*)xb + (size_t)half * 32 + row;
    const float4* xp = (const float4*)(x + (size_t)row * KDIM + half * 8);

    f32x16 acc;
#pragma unroll
    for (int i = 0; i < 16; ++i) acc[i] = 0.0f;

#pragma unroll 8
    for (int s = 0; s < 256; ++s) {
        float4 w0 = wp[s * 4], w1 = wp[s * 4 + 1];
        uint4 bb;
        bb.x = ternpack(w0.x, w0.y, delta);
        bb.y = ternpack(w0.z, w0.w, delta);
        bb.z = ternpack(w1.x, w1.y, delta);
        bb.w = ternpack(w1.z, w1.w, delta);
        bf16x8 av;
        if constexpr (XBF) {
            av = __builtin_bit_cast(bf16x8, xa[(size_t)s * 64]);
        } else {
            float4 v0 = xp[s * 4], v1 = xp[s * 4 + 1];
            struct U { ushort s[8]; } uu;
            uu.s[0] = f2bf(v0.x); uu.s[1] = f2bf(v0.y);
            uu.s[2] = f2bf(v0.z); uu.s[3] = f2bf(v0.w);
            uu.s[4] = f2bf(v1.x); uu.s[5] = f2bf(v1.y);
            uu.s[6] = f2bf(v1.z); uu.s[7] = f2bf(v1.w);
            av = __builtin_bit_cast(bf16x8, uu);
        }
        acc = __builtin_amdgcn_mfma_f32_32x32x16_bf16(
                  av, __builtin_bit_cast(bf16x8, bb), acc, 0, 0, 0);
    }
    const float a = *alpha;
#pragma unroll
    for (int rg = 0; rg < 16; ++rg) {
        const int m = (rg & 3) + 8 * (rg >> 2) + 4 * half;
        const int n = o0 + row;
        dst[(size_t)m * OUTN + n] = fmaf(a, acc[rg], bias[n]);
    }
}

// ---------------- pass 3: combine K-split partials + alpha + bias ----------------
__global__ __launch_bounds__(256) void combine_k(const float4* __restrict__ part,
                                                 const float* __restrict__ alpha,
                                                 const float4* __restrict__ bias4,
                                                 float4* __restrict__ out4) {
    const int i = blockIdx.x * 256 + threadIdx.x;   // exactly 88064
    const float a = *alpha;
    float4 s = part[i];
#pragma unroll
    for (int k = 1; k < NKS; ++k) {
        float4 p = part[i + (size_t)k * (BDIM * OUTN / 4)];
        s.x += p.x; s.y += p.y; s.z += p.z; s.w += p.w;
    }
    const float4 b = bias4[i % (OUTN / 4)];
    float4 o;
    o.x = fmaf(a, s.x, b.x); o.y = fmaf(a, s.y, b.y);
    o.z = fmaf(a, s.z, b.z); o.w = fmaf(a, s.w, b.w);
    out4[i] = o;
}

extern "C" void kernel_launch(void* const* d_in, const int* in_sizes, int n_in,
                              void* d_out, int out_size, void* d_ws, size_t ws_size,
                              hipStream_t stream) {
    const float* x     = (const float*)d_in[0];
    const float* W     = (const float*)d_in[1];
    const float* alpha = (const float*)d_in[2];
    const float* bias  = (const float*)d_in[3];
    float* out = (float*)d_out;

    double* dsum = (double*)d_ws;
    const size_t XBF_OFF = 1024;
    const size_t XBF_SZ  = (size_t)BDIM * KDIM * 2;              // 256 KiB
    const size_t PART_OFF = XBF_OFF + XBF_SZ;
    const size_t PART_SZ  = (size_t)NKS * BDIM * OUTN * 4;       // 22.5 MiB

    const bool use_xbf = ws_size >= XBF_OFF + XBF_SZ;
    const bool use_ks  = use_xbf && ws_size >= PART_OFF + PART_SZ;

    ushort* xb = (ushort*)((char*)d_ws + XBF_OFF);
    if (use_xbf) {
        xconv_k<<<128, 256, 0, stream>>>(x, xb, dsum);           // also zeroes dsum
    } else {
        (void)hipMemsetAsync(d_ws, 0, 64, stream);
    }

    abssum_k<<<1024, 256, 0, stream>>>((const float4*)W, dsum);

    if (use_ks) {
        float* part = (float*)((char*)d_ws + PART_OFF);
        gemm_k<<<NT * NKS, 64, 0, stream>>>(W, xb, dsum, part);
        combine_k<<<344, 256, 0, stream>>>((const float4*)part, alpha,
                                           (const float4*)bias, (float4*)out);
    } else if (use_xbf) {
        gemm1_k<true><<<NT, 64, 0, stream>>>(W, x, xb, dsum, out, alpha, bias);
    } else {
        gemm1_k<false><<<NT, 64, 0, stream>>>(W, x, nullptr, dsum, out, alpha, bias);
    }
}